// Round 10
// baseline (189.776 us; speedup 1.0000x reference)
//
#include <hip/hip_runtime.h>
#include <hip/hip_fp16.h>

#define H_  64      // B*N heads
#define D_  128
#define L_  2048
#define PRE 0.35709578f   // sqrt(log2(e)/sqrt(128)); exp(S/sqrt(D)) = 2^(S')
#define SLOTS 17          // 0..14: off-diag col partials | 15: row-acc | 16: diag

typedef _Float16 half8 __attribute__((ext_vector_type(8)));
typedef float    f32x4 __attribute__((ext_vector_type(4)));

// RAW v_exp_f32 (R8->R9 lesson: libm exp2f expansion cost ~18us kernel-wide).
__device__ __forceinline__ float fast_exp2(float x) {
#if __has_builtin(__builtin_amdgcn_exp2f)
    return __builtin_amdgcn_exp2f(x);
#else
    return __builtin_exp2f(x);
#endif
}

__device__ __forceinline__ void gload16(const void* g, void* l) {
    __builtin_amdgcn_global_load_lds(
        (const __attribute__((address_space(1))) void*)g,
        (__attribute__((address_space(3))) void*)l,
        16, 0, 0);
}

// Stage 16KB (64 rows x 256B) with 4 waves: 4 instrs/wave.
// Linear LDS dest, pre-swizzled global src (byte ^= (row&7)<<4 per 256B row).
__device__ __forceinline__ void stage16k(const char* __restrict__ src,
                                         char* __restrict__ dst,
                                         int wid, int lane) {
#pragma unroll
    for (int jj = 0; jj < 4; ++jj) {
        const unsigned o   = (unsigned)(wid * 4 + jj) * 1024u + (unsigned)lane * 16u;
        const unsigned row = o >> 8;
        const unsigned so  = (o & ~255u) | ((o & 255u) ^ ((row & 7u) << 4));
        gload16(src + so, dst + (size_t)(wid * 4 + jj) * 1024u);
    }
}

// ---------------------------------------------------------------------------
// Kernel 1: x [H][D][L] fp32 -> xt [H][L][D] fp16, scaled by PRE
// ---------------------------------------------------------------------------
__global__ __launch_bounds__(256) void k_transpose(const float* __restrict__ x,
                                                   __half* __restrict__ xt) {
    const int h  = blockIdx.x;
    const int lc = blockIdx.y;
    __shared__ float raw[128][65];
    const float* xh = x + (size_t)h * D_ * L_ + (size_t)lc * 64;
    const int t = threadIdx.x;
    const int r0 = t >> 4;
    const int c4 = (t & 15) << 2;
#pragma unroll
    for (int i = 0; i < 8; ++i) {
        const int d = i * 16 + r0;
        const float4 v = *(const float4*)(xh + (size_t)d * L_ + c4);
        raw[d][c4 + 0] = v.x; raw[d][c4 + 1] = v.y;
        raw[d][c4 + 2] = v.z; raw[d][c4 + 3] = v.w;
    }
    __syncthreads();
    const int lane = t & 63, w = t >> 6;
    __half2* xth = (__half2*)(xt + (size_t)h * L_ * D_ + (size_t)lc * 64 * D_);
#pragma unroll
    for (int i = 0; i < 16; ++i) {
        const int jl = w * 16 + i;
        const float a = raw[2 * lane][jl] * PRE;
        const float b = raw[2 * lane + 1][jl] * PRE;
        xth[(size_t)jl * 64 + lane] = __floats2half2_rn(a, b);
    }
}

// ---------------------------------------------------------------------------
// Kernel 2: symmetric panel-persistent Gram GEMM, 64-col streamed B.
//   256 thr = 4 waves (2x2; wave tile 64 rows x 32 cols). One block per
//   (head, 128-row panel p): steps i=0..31-2p over 64-col tiles cc=2p+i.
//   Steps 0,1 are the diagonal: the two B buffers hold the A halves staged
//   at panel start (afr also loaded from them), consumed in place before
//   streaming overwrites them. A-frags live in registers all panel.
//   LDS 43KB -> 3 blocks/CU (3 waves/SIMD; R9 was latency-bound at 2).
//   ONE __syncthreads per step; csum parity-flushed during the next step.
// ---------------------------------------------------------------------------
template <int PASS>
__global__ __launch_bounds__(256, 3) void k_gemm(const __half* __restrict__ xt,
                                                 const float* __restrict__ ainv,
                                                 float* __restrict__ zw) {
    __shared__ char  sm[32768];        // two 16KB buffers: A halves, then B dbuf
    __shared__ float aS[2048];
    __shared__ float csum[2][2][64];
    __shared__ float zfin[2][128];

    const int bid = blockIdx.x;
    const int res = bid & 7;           // XCD pinning
    const int j   = bid >> 3;
    const int h   = ((j >> 4) << 3) | res;
    const int p   = j & 15;            // ascending: big panels dispatch first
    const int NTOT = 32 - 2 * p;       // 2 diag + (30-2p) off-diag 64-col steps

    const int t    = threadIdx.x;
    const int lane = t & 63;
    const int wid  = t >> 6;           // 0..3
    const int wr   = wid >> 1;         // 0..1: 64-row group
    const int wc   = wid & 1;          // 0..1: 32-col group
    const int lo   = lane & 15, hi = lane >> 4;
    const unsigned sx   = (unsigned)((lane & 7) << 4);
    const unsigned rowB = (unsigned)(wc * 32 + lo);

    const char* xh  = (const char*)(xt + (size_t)h * (L_ * D_));
    float*      zwh = zw + (size_t)h * SLOTS * 2048;

    if (PASS == 2) {                   // ainv -> LDS once
        const float4* a4 = (const float4*)(ainv + ((size_t)h << 11));
        *(float4*)&aS[t * 8]     = a4[t * 2];
        *(float4*)&aS[t * 8 + 4] = a4[t * 2 + 1];
    }

    // ---- stage A halves (= diag tiles cc=2p, 2p+1) into the two buffers
    stage16k(xh + (size_t)(2 * p) * 16384, sm, wid, lane);
    stage16k(xh + (size_t)(2 * p + 1) * 16384, sm + 16384, wid, lane);
    __syncthreads();

    // ---- A fragments -> registers (live whole panel); wave's rows in buf[wr]
    half8 afr[4][4];
#pragma unroll
    for (int f = 0; f < 4; ++f)
#pragma unroll
        for (int s = 0; s < 4; ++s)
            afr[f][s] = *(const half8*)(sm + wr * 16384 + (unsigned)(f * 16 + lo) * 256
                                           + (((unsigned)(s * 64 + hi * 16)) ^ sx));
    float rs[4][4] = {};               // pass1: row sums; pass2: sym row-weighted
    float ar[4][4];
    if (PASS == 2) {
#pragma unroll
        for (int fm = 0; fm < 4; ++fm)
#pragma unroll
            for (int r = 0; r < 4; ++r)
                ar[fm][r] = aS[p * 128 + wr * 64 + fm * 16 + hi * 4 + r];
    }

#pragma unroll 1
    for (int i = 0; i < NTOT; ++i) {
        const int cc = 2 * p + i;
        if (i > 0) __syncthreads();    // B(i) drained+visible; csum(i-1) visible
        if (i >= 1 && i + 1 < NTOT)    // stage next tile into the freed buffer
            stage16k(xh + (size_t)(cc + 1) * 16384,
                     sm + (((i + 1) & 1) ? 16384 : 0), wid, lane);
        if (i >= 1 && t < 64) {        // flush prev step's column partials
            const int jj = i - 1, c2 = 2 * p + jj;
            const float v = csum[jj & 1][0][t] + csum[jj & 1][1][t];
            if (jj < 2) { if (PASS == 2) zwh[((size_t)16 << 11) + (size_t)c2 * 64 + t] = v; }
            else        zwh[((size_t)p << 11) + (size_t)c2 * 64 + t] = v;
        }

        const char* bbuf = sm + ((i & 1) ? 16384 : 0);
        float acol[2];
        if (PASS == 2) {
#pragma unroll
            for (int f = 0; f < 2; ++f)
                acol[f] = aS[cc * 64 + wc * 32 + f * 16 + lo];
        }

        f32x4 acc[4][2] = {};
        __builtin_amdgcn_s_setprio(1);
#pragma unroll
        for (int s = 0; s < 4; ++s) {
            const unsigned inr = ((unsigned)(s * 64 + hi * 16)) ^ sx;
            half8 b[2];
#pragma unroll
            for (int f = 0; f < 2; ++f)
                b[f] = *(const half8*)(bbuf + (rowB + (unsigned)f * 16) * 256 + inr);
#pragma unroll
            for (int fm = 0; fm < 4; ++fm)
#pragma unroll
                for (int fn = 0; fn < 2; ++fn)
                    acc[fm][fn] = __builtin_amdgcn_mfma_f32_16x16x32_f16(
                        afr[fm][s], b[fn], acc[fm][fn], 0, 0, 0);
        }
        __builtin_amdgcn_s_setprio(0);

        float cs[2] = {0.f, 0.f};
#pragma unroll
        for (int fm = 0; fm < 4; ++fm)
#pragma unroll
            for (int fn = 0; fn < 2; ++fn)
#pragma unroll
                for (int r = 0; r < 4; ++r) {
                    const float e = fast_exp2(acc[fm][fn][r]);
                    if (PASS == 1) { rs[fm][r] += e; cs[fn] += e; }
                    else           { cs[fn] += ar[fm][r] * e;
                                     if (i >= 2) rs[fm][r] += acol[fn] * e; }
                }
        if (!(PASS == 1 && i < 2)) {   // pass1 diag: rows only (no double count)
#pragma unroll
            for (int fn = 0; fn < 2; ++fn) {
                cs[fn] += __shfl_xor(cs[fn], 16, 64);
                cs[fn] += __shfl_xor(cs[fn], 32, 64);
            }
            if (lane < 16) {
#pragma unroll
                for (int fn = 0; fn < 2; ++fn)
                    csum[i & 1][wr][wc * 32 + fn * 16 + lane] = cs[fn];
            }
        }
    }

    // ---- panel end: rs over 16 col-lanes; flush zfin + last csum column
#pragma unroll
    for (int fm = 0; fm < 4; ++fm)
#pragma unroll
        for (int r = 0; r < 4; ++r) {
            float v = rs[fm][r];
            v += __shfl_xor(v, 1, 64);
            v += __shfl_xor(v, 2, 64);
            v += __shfl_xor(v, 4, 64);
            v += __shfl_xor(v, 8, 64);
            if (lo == 0) zfin[wc][wr * 64 + fm * 16 + hi * 4 + r] = v;
        }
    __syncthreads();
    if (t < 128)
        zwh[((size_t)15 << 11) + ((size_t)p << 7) + t] = zfin[0][t] + zfin[1][t];
    if (t < 64) {
        const int jj = NTOT - 1, c2 = 2 * p + jj;
        const float v = csum[jj & 1][0][t] + csum[jj & 1][1][t];
        if (jj < 2) { if (PASS == 2) zwh[((size_t)16 << 11) + (size_t)c2 * 64 + t] = v; }
        else        zwh[((size_t)p << 11) + (size_t)c2 * 64 + t] = v;
    }
}

// ---------------------------------------------------------------------------
// Kernel 3: Z[l] = slot15 + sum_{p<q} slot_p ; Ainv = 1/Z   (q = l>>7)
// ---------------------------------------------------------------------------
__global__ __launch_bounds__(256) void k_reduceZ(const float* __restrict__ zp,
                                                 float* __restrict__ ainv) {
    const int i = blockIdx.x * 256 + threadIdx.x;   // over H_*L_
    const int h = i >> 11, l = i & 2047, q = l >> 7;
    const float* zh = zp + (size_t)h * SLOTS * 2048;
    float z = zh[((size_t)15 << 11) + l];
#pragma unroll
    for (int p = 0; p < 15; ++p)
        if (p < q) z += zh[((size_t)p << 11) + l];
    ainv[i] = 1.0f / z;
}

// ---------------------------------------------------------------------------
// Kernel 4: w = slot15 + slot16 + sum_{p<q} slot_p ; out = (1/L) x . w
// ---------------------------------------------------------------------------
__global__ __launch_bounds__(256) void k_out(const float* __restrict__ x,
                                             const float* __restrict__ wp,
                                             float* __restrict__ out) {
    __shared__ float wl[L_];
    const int h = blockIdx.x >> 2, qb = blockIdx.x & 3;
    const int t = threadIdx.x, lane = t & 63, wid = t >> 6;
    const float* wh = wp + (size_t)h * SLOTS * 2048;
    for (int c = t; c < L_; c += 256) {
        const int q = c >> 7;
        float s = wh[((size_t)15 << 11) + c] + wh[((size_t)16 << 11) + c];
#pragma unroll
        for (int p = 0; p < 15; ++p)
            if (p < q) s += wh[((size_t)p << 11) + c];
        wl[c] = s;
    }
    __syncthreads();
#pragma unroll 1
    for (int it = 0; it < 8; ++it) {
        const int d = qb * 32 + wid * 8 + it;
        const float* xr = x + ((size_t)h * D_ + d) * L_;
        float s = 0.0f;
#pragma unroll
        for (int kk = 0; kk < 8; ++kk) {
            const int m = kk * 256 + lane * 4;
            const float4 xv = *(const float4*)(xr + m);
            const float4 wv = *(const float4*)(wl + m);
            s += xv.x * wv.x + xv.y * wv.y + xv.z * wv.z + xv.w * wv.w;
        }
#pragma unroll
        for (int dm = 1; dm < 64; dm <<= 1) s += __shfl_xor(s, dm, 64);
        if (lane == 0) out[(size_t)h * D_ + d] = s * (1.0f / (float)L_);
    }
}

// ---------------------------------------------------------------------------
extern "C" void kernel_launch(void* const* d_in, const int* in_sizes, int n_in,
                              void* d_out, int out_size, void* d_ws, size_t ws_size,
                              hipStream_t stream) {
    const float* x = (const float*)d_in[0];
    float* out = (float*)d_out;
    char* ws = (char*)d_ws;

    // workspace: xt 33,554,432 | zwp 17 slots = 8,912,896 | ainv 524,288
    __half* xt  = (__half*)(ws);
    float* zwp  = (float*)(ws + 33554432);
    float* ainv = (float*)(ws + 33554432 + 8912896);

    k_transpose<<<dim3(H_, L_ / 64), 256, 0, stream>>>(x, xt);
    k_gemm<1><<<1024, 256, 0, stream>>>(xt, ainv, zwp);
    k_reduceZ<<<(H_ * L_) / 256, 256, 0, stream>>>(zwp, ainv);
    k_gemm<2><<<1024, 256, 0, stream>>>(xt, ainv, zwp);
    k_out<<<H_ * 4, 256, 0, stream>>>(x, zwp, out);
}

// Round 11
// 188.900 us; speedup vs baseline: 1.0046x; 1.0046x over previous
//
#include <hip/hip_runtime.h>
#include <hip/hip_fp16.h>

#define H_  64      // B*N heads
#define D_  128
#define L_  2048
#define PRE 0.35709578f   // sqrt(log2(e)/sqrt(128)); exp(S/sqrt(D)) = 2^(S')
#define SLOTS 17          // 0..14: off-diag col partials | 15: row-acc | 16: diag

typedef _Float16 half8 __attribute__((ext_vector_type(8)));
typedef float    f32x4 __attribute__((ext_vector_type(4)));

// RAW v_exp_f32 (R8->R9 lesson: libm exp2f expansion cost ~18us kernel-wide).
__device__ __forceinline__ float fast_exp2(float x) {
#if __has_builtin(__builtin_amdgcn_exp2f)
    return __builtin_amdgcn_exp2f(x);
#else
    return __builtin_exp2f(x);
#endif
}

__device__ __forceinline__ void gload16(const void* g, void* l) {
    __builtin_amdgcn_global_load_lds(
        (const __attribute__((address_space(1))) void*)g,
        (__attribute__((address_space(3))) void*)l,
        16, 0, 0);
}

// Stage 32KB (128 rows x 256B) with 8 waves: 4 instrs/wave.
// Linear LDS dest, pre-swizzled global src (byte ^= (row&7)<<4 per 256B row).
__device__ __forceinline__ void stage32k8(const char* __restrict__ src,
                                          char* __restrict__ dst,
                                          int wid, int lane) {
#pragma unroll
    for (int jj = 0; jj < 4; ++jj) {
        const unsigned o   = (unsigned)(wid * 4 + jj) * 1024u + (unsigned)lane * 16u;
        const unsigned row = o >> 8;
        const unsigned so  = (o & ~255u) | ((o & 255u) ^ ((row & 7u) << 4));
        gload16(src + so, dst + (size_t)(wid * 4 + jj) * 1024u);
    }
}

// ---------------------------------------------------------------------------
// Kernel 1: x [H][D][L] fp32 -> xt [H][L][D] fp16, scaled by PRE
// ---------------------------------------------------------------------------
__global__ __launch_bounds__(256) void k_transpose(const float* __restrict__ x,
                                                   __half* __restrict__ xt) {
    const int h  = blockIdx.x;
    const int lc = blockIdx.y;
    __shared__ float raw[128][65];
    const float* xh = x + (size_t)h * D_ * L_ + (size_t)lc * 64;
    const int t = threadIdx.x;
    const int r0 = t >> 4;
    const int c4 = (t & 15) << 2;
#pragma unroll
    for (int i = 0; i < 8; ++i) {
        const int d = i * 16 + r0;
        const float4 v = *(const float4*)(xh + (size_t)d * L_ + c4);
        raw[d][c4 + 0] = v.x; raw[d][c4 + 1] = v.y;
        raw[d][c4 + 2] = v.z; raw[d][c4 + 3] = v.w;
    }
    __syncthreads();
    const int lane = t & 63, w = t >> 6;
    __half2* xth = (__half2*)(xt + (size_t)h * L_ * D_ + (size_t)lc * 64 * D_);
#pragma unroll
    for (int i = 0; i < 16; ++i) {
        const int jl = w * 16 + i;
        const float a = raw[2 * lane][jl] * PRE;
        const float b = raw[2 * lane + 1][jl] * PRE;
        xth[(size_t)jl * 64 + lane] = __floats2half2_rn(a, b);
    }
}

// ---------------------------------------------------------------------------
// Kernel 2: symmetric panel-persistent Gram GEMM, high-occupancy variant.
//   512 thr = 8 waves (4 row-groups x 2 col-groups; wave tile 32x64).
//   A-frags in registers from GLOBAL (32 VGPR; no A in LDS). B tiles
//   (incl diag) double-buffered in LDS, staged by all 8 waves. ONE
//   __syncthreads per step (R7-validated schedule); csum parity-flushed
//   during the next step. Balanced (p,15-p) pairing: uniform 17 steps.
//   LDS 69KB, regs ~110 <= 128 cap from __launch_bounds__(512,2)
//   (CUDA-style min-blocks: 2 blocks/CU = 16 waves/CU = 4 waves/SIMD —
//   R9/R10 were latency-bound at ~8 waves/CU).
// ---------------------------------------------------------------------------
template <int PASS>
__global__ __launch_bounds__(512, 2) void k_gemm(const __half* __restrict__ xt,
                                                 const float* __restrict__ ainv,
                                                 float* __restrict__ zw) {
    __shared__ char  smB[2][32768];
    __shared__ float csum[2][4][128];
    __shared__ float zfin[2][128];

    const int bid = blockIdx.x;
    const int res = bid & 7;           // XCD pinning
    const int j   = bid >> 3;
    const int h   = ((j >> 3) << 3) | res;
    const int pid = j & 7;

    const int t    = threadIdx.x;
    const int lane = t & 63;
    const int wid  = t >> 6;           // 0..7
    const int wr   = wid >> 1;         // 0..3: 32-row group
    const int wc   = wid & 1;          // 0..1: 64-col group
    const int lo   = lane & 15, hi = lane >> 4;
    const unsigned sx = (unsigned)((lane & 7) << 4);

    const char*  xh  = (const char*)(xt + (size_t)h * (L_ * D_));
    float*       zwh = zw + (size_t)h * SLOTS * 2048;
    const float* ah  = ainv + ((size_t)h << 11);

#pragma unroll 1
    for (int pp = 0; pp < 2; ++pp) {
        const int p  = pp ? (15 - pid) : pid;
        const int NS = 15 - p;         // steps it=0..NS, ct=p+it (it=0 diag)

        stage32k8(xh + (size_t)p * 32768, smB[0], wid, lane);

        // ---- A fragments (32 rows) -> registers, straight from global
        half8 afr[2][4];
#pragma unroll
        for (int fm = 0; fm < 2; ++fm)
#pragma unroll
            for (int s = 0; s < 4; ++s)
                afr[fm][s] = *(const half8*)(xh
                    + (size_t)(p * 128 + wr * 32 + fm * 16 + lo) * 256
                    + (unsigned)(s * 64 + hi * 16));
        float rs[2][4] = {};           // pass1: row sums; pass2: sym row-weighted
        float ar[2][4];
        if (PASS == 2) {
#pragma unroll
            for (int fm = 0; fm < 2; ++fm)
#pragma unroll
                for (int r = 0; r < 4; ++r)
                    ar[fm][r] = ah[p * 128 + wr * 32 + fm * 16 + hi * 4 + r];
        }
        __syncthreads();               // B(0) landed; prev-panel LDS consumed

#pragma unroll 1
        for (int it = 0; it <= NS; ++it) {
            const int ct = p + it;
            if (it > 0) __syncthreads();            // B(it) drained+visible
            if (it < NS)
                stage32k8(xh + (size_t)(ct + 1) * 32768,
                          smB[(it + 1) & 1], wid, lane);
            if (it >= 1 && t < 128) {               // flush prev step's cols
                const int pr = (it - 1) & 1;
                const float v = csum[pr][0][t] + csum[pr][1][t]
                              + csum[pr][2][t] + csum[pr][3][t];
                if (it == 1) { if (PASS == 2) zwh[((size_t)16 << 11) + (size_t)p * 128 + t] = v; }
                else         zwh[((size_t)p << 11) + (size_t)(ct - 1) * 128 + t] = v;
            }

            const char* bbuf = smB[it & 1];
            float acol[4];
            if (PASS == 2) {
#pragma unroll
                for (int fn = 0; fn < 4; ++fn)
                    acol[fn] = ah[ct * 128 + wc * 64 + fn * 16 + lo];
            }

            f32x4 acc[2][4] = {};
            __builtin_amdgcn_s_setprio(1);
#pragma unroll
            for (int s = 0; s < 4; ++s) {
                const unsigned inr = ((unsigned)(s * 64 + hi * 16)) ^ sx;
                half8 b[4];
#pragma unroll
                for (int fn = 0; fn < 4; ++fn)
                    b[fn] = *(const half8*)(bbuf
                        + (unsigned)(wc * 64 + fn * 16 + lo) * 256 + inr);
#pragma unroll
                for (int fm = 0; fm < 2; ++fm)
#pragma unroll
                    for (int fn = 0; fn < 4; ++fn)
                        acc[fm][fn] = __builtin_amdgcn_mfma_f32_16x16x32_f16(
                            afr[fm][s], b[fn], acc[fm][fn], 0, 0, 0);
            }
            __builtin_amdgcn_s_setprio(0);

            float cs[4] = {0.f, 0.f, 0.f, 0.f};
#pragma unroll
            for (int fm = 0; fm < 2; ++fm)
#pragma unroll
                for (int fn = 0; fn < 4; ++fn)
#pragma unroll
                    for (int r = 0; r < 4; ++r) {
                        const float e = fast_exp2(acc[fm][fn][r]);
                        if (PASS == 1) { rs[fm][r] += e; cs[fn] += e; }
                        else           { cs[fn] += ar[fm][r] * e;
                                         if (it > 0) rs[fm][r] += acol[fn] * e; }
                    }
            if (!(PASS == 1 && it == 0)) {          // pass1 diag: rows only
#pragma unroll
                for (int fn = 0; fn < 4; ++fn) {
                    cs[fn] += __shfl_xor(cs[fn], 16, 64);
                    cs[fn] += __shfl_xor(cs[fn], 32, 64);
                }
                if (lane < 16) {
#pragma unroll
                    for (int fn = 0; fn < 4; ++fn)
                        csum[it & 1][wr][wc * 64 + fn * 16 + lane] = cs[fn];
                }
            }
        }

        // ---- panel end: rs over 16 col-lanes; flush zfin + last csum column
#pragma unroll
        for (int fm = 0; fm < 2; ++fm)
#pragma unroll
            for (int r = 0; r < 4; ++r) {
                float v = rs[fm][r];
                v += __shfl_xor(v, 1, 64);
                v += __shfl_xor(v, 2, 64);
                v += __shfl_xor(v, 4, 64);
                v += __shfl_xor(v, 8, 64);
                if (lo == 0) zfin[wc][wr * 32 + fm * 16 + hi * 4 + r] = v;
            }
        __syncthreads();
        if (t < 128) {
            zwh[((size_t)15 << 11) + ((size_t)p << 7) + t] = zfin[0][t] + zfin[1][t];
            const int pr = NS & 1;
            const float v = csum[pr][0][t] + csum[pr][1][t]
                          + csum[pr][2][t] + csum[pr][3][t];
            if (NS == 0) { if (PASS == 2) zwh[((size_t)16 << 11) + (size_t)p * 128 + t] = v; }
            else         zwh[((size_t)p << 11) + (size_t)(p + NS) * 128 + t] = v;
        }
    }
}

// ---------------------------------------------------------------------------
// Kernel 3: Z[l] = slot15 + sum_{p<q} slot_p ; Ainv = 1/Z   (q = l>>7)
// ---------------------------------------------------------------------------
__global__ __launch_bounds__(256) void k_reduceZ(const float* __restrict__ zp,
                                                 float* __restrict__ ainv) {
    const int i = blockIdx.x * 256 + threadIdx.x;   // over H_*L_
    const int h = i >> 11, l = i & 2047, q = l >> 7;
    const float* zh = zp + (size_t)h * SLOTS * 2048;
    float z = zh[((size_t)15 << 11) + l];
#pragma unroll
    for (int p = 0; p < 15; ++p)
        if (p < q) z += zh[((size_t)p << 11) + l];
    ainv[i] = 1.0f / z;
}

// ---------------------------------------------------------------------------
// Kernel 4: w = slot15 + slot16 + sum_{p<q} slot_p ; out = (1/L) x . w
// ---------------------------------------------------------------------------
__global__ __launch_bounds__(256) void k_out(const float* __restrict__ x,
                                             const float* __restrict__ wp,
                                             float* __restrict__ out) {
    __shared__ float wl[L_];
    const int h = blockIdx.x >> 2, qb = blockIdx.x & 3;
    const int t = threadIdx.x, lane = t & 63, wid = t >> 6;
    const float* wh = wp + (size_t)h * SLOTS * 2048;
    for (int c = t; c < L_; c += 256) {
        const int q = c >> 7;
        float s = wh[((size_t)15 << 11) + c] + wh[((size_t)16 << 11) + c];
#pragma unroll
        for (int p = 0; p < 15; ++p)
            if (p < q) s += wh[((size_t)p << 11) + c];
        wl[c] = s;
    }
    __syncthreads();
#pragma unroll 1
    for (int it = 0; it < 8; ++it) {
        const int d = qb * 32 + wid * 8 + it;
        const float* xr = x + ((size_t)h * D_ + d) * L_;
        float s = 0.0f;
#pragma unroll
        for (int kk = 0; kk < 8; ++kk) {
            const int m = kk * 256 + lane * 4;
            const float4 xv = *(const float4*)(xr + m);
            const float4 wv = *(const float4*)(wl + m);
            s += xv.x * wv.x + xv.y * wv.y + xv.z * wv.z + xv.w * wv.w;
        }
#pragma unroll
        for (int dm = 1; dm < 64; dm <<= 1) s += __shfl_xor(s, dm, 64);
        if (lane == 0) out[(size_t)h * D_ + d] = s * (1.0f / (float)L_);
    }
}

// ---------------------------------------------------------------------------
extern "C" void kernel_launch(void* const* d_in, const int* in_sizes, int n_in,
                              void* d_out, int out_size, void* d_ws, size_t ws_size,
                              hipStream_t stream) {
    const float* x = (const float*)d_in[0];
    float* out = (float*)d_out;
    char* ws = (char*)d_ws;

    // workspace: xt 33,554,432 | zwp 17 slots = 8,912,896 | ainv 524,288
    __half* xt  = (__half*)(ws);
    float* zwp  = (float*)(ws + 33554432);
    float* ainv = (float*)(ws + 33554432 + 8912896);

    k_transpose<<<dim3(H_, L_ / 64), 256, 0, stream>>>(x, xt);
    k_gemm<1><<<512, 512, 0, stream>>>(xt, ainv, zwp);
    k_reduceZ<<<(H_ * L_) / 256, 256, 0, stream>>>(zwp, ainv);
    k_gemm<2><<<512, 512, 0, stream>>>(xt, ainv, zwp);
    k_out<<<H_ * 4, 256, 0, stream>>>(x, zwp, out);
}